// Round 2
// baseline (2502.424 us; speedup 1.0000x reference)
//
#include <hip/hip_runtime.h>
#include <stdint.h>

#define B_   4096
#define H_   512
#define G4   2048      // 4*H gates
#define T_   16
#define VOC  66
#define PADT 64
#define BOST 65

// ---------------- threefry2x32 (exact JAX schedule) ----------------
__host__ __device__ inline void tf2x32(uint32_t k0, uint32_t k1,
                                       uint32_t x0, uint32_t x1,
                                       uint32_t& o0, uint32_t& o1) {
  uint32_t ks2 = k0 ^ k1 ^ 0x1BD11BDAu;
  x0 += k0; x1 += k1;
  uint32_t ks[3] = {k1, ks2, k0};
  const int R[2][4] = {{13,15,26,6},{17,29,16,24}};
#pragma unroll
  for (int i = 0; i < 5; ++i) {
    const int* r = R[i & 1];
#pragma unroll
    for (int j = 0; j < 4; ++j) {
      x0 += x1;
      x1 = (x1 << r[j]) | (x1 >> (32 - r[j]));
      x1 ^= x0;
    }
    x0 += ks[0];
    x1 += ks[1] + (uint32_t)(i + 1);
    uint32_t tmp = ks[0]; ks[0] = ks[1]; ks[1] = ks[2]; ks[2] = tmp;
  }
  o0 = x0; o1 = x1;
}

__device__ inline float sigm(float x) { return 1.0f / (1.0f + expf(-x)); }

// ---------------- prep: reorder Whh into gate-interleaved rows, biases, Wp^T ----------------
__global__ void k_prep(const float* __restrict__ Whh, const float* __restrict__ bih,
                       const float* __restrict__ bhh, const float* __restrict__ Wp,
                       float* __restrict__ Wr, float* __restrict__ br, float* __restrict__ WpT)
{
  int idx = blockIdx.x * 256 + threadIdx.x;
  if (idx < G4 * H_) {
    int n = idx >> 9, k = idx & (H_ - 1);
    int srow = ((n & 3) << 9) + (n >> 2);   // gate-major torch row
    Wr[idx] = Whh[srow * H_ + k];
  }
  if (idx < G4) {
    int srow = ((idx & 3) << 9) + (idx >> 2);
    br[idx] = bih[srow] + bhh[srow];
  }
  if (idx < H_ * 64) {                       // WpT[k*64+a] = Wp[a*512+k]
    int k = idx >> 6, a = idx & 63;
    WpT[idx] = Wp[a * H_ + k];
  }
}

// ---------------- embW = emb @ Wih^T, gate-interleaved columns ----------------
__global__ void k_embw(const float* __restrict__ emb, const float* __restrict__ Wih,
                       float* __restrict__ embWr)
{
  int idx = blockIdx.x * 256 + threadIdx.x;   // 66*2048
  if (idx >= VOC * G4) return;
  int a = idx >> 11, n = idx & (G4 - 1);
  int srow = ((n & 3) << 9) + (n >> 2);
  const float4* e = (const float4*)(emb + a * H_);
  const float4* w = (const float4*)(Wih + srow * H_);
  float s = 0.f;
#pragma unroll 4
  for (int k = 0; k < H_ / 4; ++k) {
    float4 ev = e[k], wv = w[k];
    s = fmaf(ev.x, wv.x, s); s = fmaf(ev.y, wv.y, s);
    s = fmaf(ev.z, wv.z, s); s = fmaf(ev.w, wv.w, s);
  }
  embWr[idx] = s;
}

// ---------------- init: h=c=encoded, flags ----------------
__global__ void k_init(const float* __restrict__ enc, float* __restrict__ h0,
                       float* __restrict__ c, int* __restrict__ stopped,
                       int* __restrict__ prevAct, float* __restrict__ entSum)
{
  int i = blockIdx.x * 256 + threadIdx.x;
  if (i < B_ * H_) { float v = enc[i]; h0[i] = v; c[i] = v; }
  if (i < B_) { stopped[i] = 0; prevAct[i] = BOST; entSum[i] = 0.f; }
}

// ---------------- per-step: gates = h@Wr^T + embW[prev] + br ; fused LSTM cell ----------------
__global__ __launch_bounds__(256) void k_step(
    const float* __restrict__ Hin, const float* __restrict__ Wr,
    const float* __restrict__ embWr, const float* __restrict__ br,
    const int* __restrict__ prevAct, float* __restrict__ C,
    float* __restrict__ Hout)
{
  __shared__ float As[16][132];
  __shared__ float Bs[16][132];
  const int tid = threadIdx.x;
  const int tx = tid & 15, ty = tid >> 4;
  const int M0 = blockIdx.y * 128, N0 = blockIdx.x * 128;
  float acc[8][8];
#pragma unroll
  for (int i = 0; i < 8; i++)
#pragma unroll
    for (int j = 0; j < 8; j++) acc[i][j] = 0.f;

  const int lr = tid >> 2;           // 0..63
  const int lc = (tid & 3) << 2;     // 0,4,8,12

  for (int k0 = 0; k0 < H_; k0 += 16) {
    float4 a0 = *(const float4*)(Hin + (size_t)(M0 + lr) * H_ + k0 + lc);
    float4 a1 = *(const float4*)(Hin + (size_t)(M0 + lr + 64) * H_ + k0 + lc);
    float4 b0 = *(const float4*)(Wr + (size_t)(N0 + lr) * H_ + k0 + lc);
    float4 b1 = *(const float4*)(Wr + (size_t)(N0 + lr + 64) * H_ + k0 + lc);
    __syncthreads();
    As[lc + 0][lr] = a0.x; As[lc + 1][lr] = a0.y; As[lc + 2][lr] = a0.z; As[lc + 3][lr] = a0.w;
    As[lc + 0][lr + 64] = a1.x; As[lc + 1][lr + 64] = a1.y; As[lc + 2][lr + 64] = a1.z; As[lc + 3][lr + 64] = a1.w;
    Bs[lc + 0][lr] = b0.x; Bs[lc + 1][lr] = b0.y; Bs[lc + 2][lr] = b0.z; Bs[lc + 3][lr] = b0.w;
    Bs[lc + 0][lr + 64] = b1.x; Bs[lc + 1][lr + 64] = b1.y; Bs[lc + 2][lr + 64] = b1.z; Bs[lc + 3][lr + 64] = b1.w;
    __syncthreads();
#pragma unroll
    for (int kk = 0; kk < 16; kk++) {
      float av[8], bv[8];
#pragma unroll
      for (int i = 0; i < 8; i++) av[i] = As[kk][ty * 8 + i];
#pragma unroll
      for (int j = 0; j < 8; j++) bv[j] = Bs[kk][tx * 8 + j];
#pragma unroll
      for (int i = 0; i < 8; i++)
#pragma unroll
        for (int j = 0; j < 8; j++) acc[i][j] = fmaf(av[i], bv[j], acc[i][j]);
    }
  }

  // epilogue: add input-gates + biases, apply LSTM cell, write h,c
  const int u0 = (N0 >> 2) + tx * 2;
#pragma unroll
  for (int i = 0; i < 8; i++) {
    int row = M0 + ty * 8 + i;
    const float* ew = embWr + (size_t)prevAct[row] * G4;
    float g[8];
#pragma unroll
    for (int j = 0; j < 8; j++) {
      int n = N0 + tx * 8 + j;
      g[j] = acc[i][j] + ew[n] + br[n];
    }
#pragma unroll
    for (int w = 0; w < 2; w++) {
      int u = u0 + w;
      float ig = g[4 * w + 0], fg = g[4 * w + 1], gg = g[4 * w + 2], og = g[4 * w + 3];
      float cp = C[(size_t)row * H_ + u];
      float cn = sigm(fg) * cp + sigm(ig) * tanhf(gg);
      float hn = sigm(og) * tanhf(cn);
      C[(size_t)row * H_ + u] = cn;
      Hout[(size_t)row * H_ + u] = hn;
    }
  }
}

// ---------------- per-step: logits, log-softmax, gumbel sample, outputs ----------------
__global__ __launch_bounds__(256) void k_sample(
    const float* __restrict__ Hnew, const float* __restrict__ WpT,
    const float* __restrict__ bp, float* __restrict__ out_msg,
    float* __restrict__ out_lp, int* __restrict__ stopped,
    int* __restrict__ prevAct, float* __restrict__ entSum,
    uint32_t key0, uint32_t key1, int t)
{
  const int lane = threadIdx.x & 63;
  const int b = blockIdx.x * 4 + (threadIdx.x >> 6);
  const float* hrow = Hnew + (size_t)b * H_;

  float acc = 0.f;
#pragma unroll 4
  for (int k4 = 0; k4 < H_; k4 += 4) {
    float4 hv = *(const float4*)(hrow + k4);
    acc = fmaf(hv.x, WpT[(k4 + 0) * 64 + lane], acc);
    acc = fmaf(hv.y, WpT[(k4 + 1) * 64 + lane], acc);
    acc = fmaf(hv.z, WpT[(k4 + 2) * 64 + lane], acc);
    acc = fmaf(hv.w, WpT[(k4 + 3) * 64 + lane], acc);
  }
  acc += bp[lane];                          // logits[b][lane]

  // log_softmax
  float m = acc;
#pragma unroll
  for (int o = 32; o > 0; o >>= 1) m = fmaxf(m, __shfl_xor(m, o, 64));
  float ex = expf(acc - m);
  float s = ex;
#pragma unroll
  for (int o = 32; o > 0; o >>= 1) s += __shfl_xor(s, o, 64);
  float logp = (acc - m) - logf(s);
  float p = expf(logp);
  float pe = p * logp;
  float es = pe;
#pragma unroll
  for (int o = 32; o > 0; o >>= 1) es += __shfl_xor(es, o, 64);
  float ent = -es;

  // gumbel: JAX partitionable threefry — 64-bit counter (0, j), bits = o0 ^ o1
  uint32_t j = (uint32_t)(b * 64 + lane);   // flat index into (4096,64)
  uint32_t o0, o1; tf2x32(key0, key1, 0u, j, o0, o1);
  uint32_t bits = o0 ^ o1;
  float f = __uint_as_float(0x3F800000u | (bits >> 9)) - 1.0f;
  const float TINY = 1.17549435e-38f;
  float u = fmaxf(TINY, f + TINY);          // floats*(1-tiny)+tiny == f+tiny in fp32
  float gum = -logf(-logf(u));
  float z = gum + acc;

  // argmax, first-index tie-break
  float best = z; int bi = lane;
#pragma unroll
  for (int o = 32; o > 0; o >>= 1) {
    float ov = __shfl_xor(best, o, 64);
    int oi = __shfl_xor(bi, o, 64);
    if (ov > best || (ov == best && oi < bi)) { best = ov; bi = oi; }
  }
  float lpa = __shfl(logp, bi, 64);

  if (lane == 0) {
    int st = stopped[b];
    float live = st ? 0.f : 1.f;
    int act = st ? PADT : bi;
    out_msg[(size_t)b * T_ + t] = (float)act;
    out_lp[(size_t)b * T_ + t] = live * lpa;
    entSum[b] += live * ent;
    stopped[b] = st | (act == 0);
    prevAct[b] = act;
  }
}

// ---------------- final: msg_len, ent_avg ----------------
__global__ void k_final(const float* __restrict__ out_msg, const float* __restrict__ entSum,
                        float* __restrict__ out_len, float* __restrict__ out_ent)
{
  int b = blockIdx.x * 256 + threadIdx.x;
  if (b >= B_) return;
  int cnt = 0;
#pragma unroll
  for (int t = 0; t < T_; t++) cnt += (out_msg[(size_t)b * T_ + t] != 64.0f) ? 1 : 0;
  out_len[b] = (float)cnt;
  out_ent[b] = entSum[b] / (float)cnt;
}

extern "C" void kernel_launch(void* const* d_in, const int* in_sizes, int n_in,
                              void* d_out, int out_size, void* d_ws, size_t ws_size,
                              hipStream_t stream)
{
  const float* enc = (const float*)d_in[0];
  const float* emb = (const float*)d_in[1];
  const float* Wih = (const float*)d_in[2];
  const float* Whh = (const float*)d_in[3];
  const float* bih = (const float*)d_in[4];
  const float* bhh = (const float*)d_in[5];
  const float* Wp  = (const float*)d_in[6];
  const float* bp  = (const float*)d_in[7];

  float* out_msg = (float*)d_out;            // [4096*16]
  float* out_len = out_msg + B_ * T_;        // [4096]
  float* out_lp  = out_len + B_;             // [4096*16]
  float* out_ent = out_lp + B_ * T_;         // [4096]

  float* w = (float*)d_ws;
  float* Wr    = w;  w += G4 * H_;           // 4 MB
  float* embWr = w;  w += VOC * G4;
  float* br    = w;  w += G4;
  float* WpT   = w;  w += H_ * 64;
  float* hA    = w;  w += B_ * H_;
  float* hB    = w;  w += B_ * H_;
  float* cbuf  = w;  w += B_ * H_;
  float* entS  = w;  w += B_;
  int* stopped = (int*)w;  w += B_;
  int* prevAct = (int*)w;  w += B_;

  // step keys: partitionable threefry split — key[t] = threefry2x32((0,42), (0, t))
  uint32_t k0s[T_], k1s[T_];
  for (int t = 0; t < T_; t++) {
    uint32_t a, b2;
    tf2x32(0u, 42u, 0u, (uint32_t)t, a, b2);
    k0s[t] = a; k1s[t] = b2;
  }

  hipLaunchKernelGGL(k_prep, dim3((G4 * H_ + 255) / 256), dim3(256), 0, stream,
                     Whh, bih, bhh, Wp, Wr, br, WpT);
  hipLaunchKernelGGL(k_embw, dim3((VOC * G4 + 255) / 256), dim3(256), 0, stream,
                     emb, Wih, embWr);
  hipLaunchKernelGGL(k_init, dim3((B_ * H_ + 255) / 256), dim3(256), 0, stream,
                     enc, hA, cbuf, stopped, prevAct, entS);

  for (int t = 0; t < T_; t++) {
    const float* hin = (t & 1) ? hB : hA;
    float* hout = (t & 1) ? hA : hB;
    hipLaunchKernelGGL(k_step, dim3(G4 / 128, B_ / 128), dim3(256), 0, stream,
                       hin, Wr, embWr, br, prevAct, cbuf, hout);
    hipLaunchKernelGGL(k_sample, dim3(B_ / 4), dim3(256), 0, stream,
                       hout, WpT, bp, out_msg, out_lp, stopped, prevAct, entS,
                       k0s[t], k1s[t], t);
  }
  hipLaunchKernelGGL(k_final, dim3(B_ / 256), dim3(256), 0, stream,
                     out_msg, entS, out_len, out_ent);
}